// Round 1
// baseline (69.008 us; speedup 1.0000x reference)
//
#include <hip/hip_runtime.h>
#include <math.h>

#define NB 8
#define NN 512
#define D 128
#define ED 16
#define TI 8
#define LN_EPS 1e-5f
#define SCALE 0.08838834764831845f  // 1/sqrt(128)

__device__ __forceinline__ float dot4(float4 a, float4 b) {
    return a.x * b.x + a.y * b.y + a.z * b.z + a.w * b.w;
}

// ---------------- Kernel 1: h = x @ W^T, s_i = h.a_src, s_j = h.a_dst -------
// grid: 4096 (one block per (b,n) row), block: 128 (thread = output dim o)
__global__ __launch_bounds__(128) void k1_proj(
    const float* __restrict__ x, const float* __restrict__ W,
    const float* __restrict__ a_src, const float* __restrict__ a_dst,
    float* __restrict__ h_ws, float* __restrict__ si_ws, float* __restrict__ sj_ws)
{
    const int row = blockIdx.x;
    const int t = threadIdx.x;
    __shared__ __align__(16) float4 xl[32];
    __shared__ float r2[4];
    if (t < 32) xl[t] = ((const float4*)(x + (size_t)row * D))[t];
    __syncthreads();
    const float4* W4 = (const float4*)(W + (size_t)t * D);
    float acc = 0.f;
#pragma unroll 8
    for (int q = 0; q < 32; ++q) {
        acc += dot4(W4[q], xl[q]);
    }
    h_ws[(size_t)row * D + t] = acc;
    float vs = acc * a_src[t];
    float vd = acc * a_dst[t];
#pragma unroll
    for (int m = 32; m >= 1; m >>= 1) {
        vs += __shfl_xor(vs, m);
        vd += __shfl_xor(vd, m);
    }
    if ((t & 63) == 0) { r2[(t >> 6) * 2 + 0] = vs; r2[(t >> 6) * 2 + 1] = vd; }
    __syncthreads();
    if (t == 0) { si_ws[row] = r2[0] + r2[2]; sj_ws[row] = r2[1] + r2[3]; }
}

// ---------------- Kernel 2: scores + softmax + PV + LayerNorm ---------------
// grid: 8 batches * 64 (8 rows each) = 512 blocks, block: 256 threads
__global__ __launch_bounds__(256) void k2_attn(
    const float* __restrict__ ef, const float* __restrict__ a_e,
    const float* __restrict__ gamma, const float* __restrict__ beta,
    const float* __restrict__ h_ws, const float* __restrict__ si_ws,
    const float* __restrict__ sj_ws, float* __restrict__ out)
{
    __shared__ float sj_l[NN];
    __shared__ __align__(16) float alpha_t[NN][TI];   // [j][r] (unnormalized)
    __shared__ __align__(16) float part[4][TI][D];    // per-wave PV partials
    __shared__ float redm[TI][4];
    __shared__ float reds[TI][4];

    const int t = threadIdx.x;
    const int w = t >> 6;
    const int lane = t & 63;
    const int bid = blockIdx.x;
    const int b = bid >> 6;
    const int i0 = (bid & 63) << 3;

    sj_l[t] = sj_ws[b * NN + t];
    sj_l[t + 256] = sj_ws[b * NN + t + 256];

    const float4* ae4 = (const float4*)a_e;
    const float4 A0 = ae4[0], A1 = ae4[1], A2 = ae4[2], A3 = ae4[3];
    __syncthreads();

    // Phase A: scores for TI rows; each thread owns j = t and j = t+256
    float e0[TI], e1[TI];
#pragma unroll
    for (int r = 0; r < TI; ++r) {
        const int i = i0 + r;
        const float siv = si_ws[b * NN + i];
        const float4* efr = (const float4*)(ef + (((size_t)b * NN + i) * NN) * ED);
        const int j0 = t, j1 = t + 256;
        float s0 = dot4(efr[j0 * 4 + 0], A0) + dot4(efr[j0 * 4 + 1], A1)
                 + dot4(efr[j0 * 4 + 2], A2) + dot4(efr[j0 * 4 + 3], A3);
        float s1 = dot4(efr[j1 * 4 + 0], A0) + dot4(efr[j1 * 4 + 1], A1)
                 + dot4(efr[j1 * 4 + 2], A2) + dot4(efr[j1 * 4 + 3], A3);
        e0[r] = (siv + sj_l[j0] + s0) * SCALE;
        e1[r] = (siv + sj_l[j1] + s1) * SCALE;
        float m = fmaxf(e0[r], e1[r]);
#pragma unroll
        for (int mm = 32; mm >= 1; mm >>= 1) m = fmaxf(m, __shfl_xor(m, mm));
        if (lane == 0) redm[r][w] = m;
    }
    __syncthreads();

    // Phase B: exp + row sums; store unnormalized alpha transposed
#pragma unroll
    for (int r = 0; r < TI; ++r) {
        const float mx = fmaxf(fmaxf(redm[r][0], redm[r][1]),
                               fmaxf(redm[r][2], redm[r][3]));
        const float a0 = __expf(e0[r] - mx);
        const float a1 = __expf(e1[r] - mx);
        alpha_t[t][r] = a0;
        alpha_t[t + 256][r] = a1;
        float s = a0 + a1;
#pragma unroll
        for (int mm = 32; mm >= 1; mm >>= 1) s += __shfl_xor(s, mm);
        if (lane == 0) reds[r][w] = s;
    }
    __syncthreads();

    // Phase C: h' = alpha @ h.  thread -> 4 consecutive d, 1 of 8 j-groups
    const int dl = (t & 31) << 2;
    const int g = t >> 5;
    float acc[TI][4];
#pragma unroll
    for (int r = 0; r < TI; ++r)
#pragma unroll
        for (int c = 0; c < 4; ++c) acc[r][c] = 0.f;

    const float* hb = h_ws + (size_t)b * NN * D;
    for (int jj = 0; jj < 64; ++jj) {
        const int j = (g << 6) + jj;
        const float4 hv = *(const float4*)(hb + j * D + dl);
        const float4 al0 = *(const float4*)(&alpha_t[j][0]);
        const float4 al1 = *(const float4*)(&alpha_t[j][4]);
        const float ar[TI] = {al0.x, al0.y, al0.z, al0.w, al1.x, al1.y, al1.z, al1.w};
        const float hc[4] = {hv.x, hv.y, hv.z, hv.w};
#pragma unroll
        for (int r = 0; r < TI; ++r)
#pragma unroll
            for (int c = 0; c < 4; ++c) acc[r][c] += ar[r] * hc[c];
    }
    // combine the two j-groups that live in the same wave (lane ^ 32)
#pragma unroll
    for (int r = 0; r < TI; ++r)
#pragma unroll
        for (int c = 0; c < 4; ++c) acc[r][c] += __shfl_xor(acc[r][c], 32);
    if ((t & 63) < 32) {
#pragma unroll
        for (int r = 0; r < TI; ++r)
            *(float4*)&part[w][r][dl] = make_float4(acc[r][0], acc[r][1], acc[r][2], acc[r][3]);
    }
    __syncthreads();

    // Phase D: LayerNorm.  wave w handles rows 2w, 2w+1; lane -> d, d+64
#pragma unroll
    for (int rr = 0; rr < 2; ++rr) {
        const int r = w * 2 + rr;
        const float inv = 1.0f / (reds[r][0] + reds[r][1] + reds[r][2] + reds[r][3]);
        const int d0 = lane, d1 = lane + 64;
        const float v0 = (part[0][r][d0] + part[1][r][d0] + part[2][r][d0] + part[3][r][d0]) * inv;
        const float v1 = (part[0][r][d1] + part[1][r][d1] + part[2][r][d1] + part[3][r][d1]) * inv;
        float s = v0 + v1, q = v0 * v0 + v1 * v1;
#pragma unroll
        for (int mm = 32; mm >= 1; mm >>= 1) {
            s += __shfl_xor(s, mm);
            q += __shfl_xor(q, mm);
        }
        const float mu = s * (1.f / 128.f);
        const float var = q * (1.f / 128.f) - mu * mu;
        const float rs = rsqrtf(var + LN_EPS);
        const size_t ob = ((size_t)(b * NN + i0 + r)) * D;
        out[ob + d0] = (v0 - mu) * rs * gamma[d0] + beta[d0];
        out[ob + d1] = (v1 - mu) * rs * gamma[d1] + beta[d1];
    }
}

extern "C" void kernel_launch(void* const* d_in, const int* in_sizes, int n_in,
                              void* d_out, int out_size, void* d_ws, size_t ws_size,
                              hipStream_t stream) {
    const float* x     = (const float*)d_in[0];
    const float* ef    = (const float*)d_in[1];
    const float* W     = (const float*)d_in[2];
    const float* a_src = (const float*)d_in[3];
    const float* a_dst = (const float*)d_in[4];
    const float* a_e   = (const float*)d_in[5];
    const float* gamma = (const float*)d_in[6];
    const float* beta  = (const float*)d_in[7];
    float* out = (float*)d_out;

    float* h_ws  = (float*)d_ws;                       // 4096*128 floats = 2 MiB
    float* si_ws = h_ws + (size_t)NB * NN * D;         // 4096 floats
    float* sj_ws = si_ws + NB * NN;                    // 4096 floats

    k1_proj<<<NB * NN, 128, 0, stream>>>(x, W, a_src, a_dst, h_ws, si_ws, sj_ws);
    k2_attn<<<NB * (NN / TI), 256, 0, stream>>>(ef, a_e, gamma, beta,
                                                h_ws, si_ws, sj_ws, out);
}